// Round 1
// 196.089 us; speedup vs baseline: 1.0111x; 1.0111x over previous
//
#include <hip/hip_runtime.h>
#include <hip/hip_bf16.h>

#define SEQ 64
#define DIM 512
#define VOCAB 300
#define LDQ 516   // ushort row stride for qkv LDS: 1032B rows (8B-aligned). 8-row quad stride
                  // = 2064 dwords = 16 mod 32 banks -> 2-way aliasing only (free). A 16B-aligned
                  // stride (520) makes quad strides = 0 mod 32 -> 8-way conflicts in Phase C.
#define LDSC 72   // ushort row stride for scores (144B rows, 16B-aligned)

typedef __attribute__((ext_vector_type(8))) short short8;   // 8 bf16 (MFMA A/B frag)
typedef __attribute__((ext_vector_type(4))) float floatx4;  // MFMA C/D frag

static __device__ inline unsigned short f2bf(float x) {
    __hip_bfloat16 t = __float2bfloat16(x);
    return *reinterpret_cast<unsigned short*>(&t);
}

// load 8 bf16 from an 8B-aligned LDS address (two uint2 -> ds_read2_b64)
static __device__ inline short8 ld8(const unsigned short* p) {
    union { short8 s; uint2 u[2]; } r;
    r.u[0] = *(const uint2*)p;
    r.u[1] = *(const uint2*)(p + 4);
    return r.s;
}

// ---- prep: P = emb @ Qdense (300x512 @ 512x512, bf16 out), reading Qdense
// transposed directly (1 MB, L2-resident, read once by 5 blocks — coalescing
// irrelevant at 157 MFLOP). Grid 5 x 512 thr.
__global__ __launch_bounds__(512) void proj_kernel(
    const float* __restrict__ emb,   // fp32 [300][512]
    const float* __restrict__ Q,     // fp32 [512][512], row-major [k][n]
    __hip_bfloat16* __restrict__ P)  // bf16 [300][512]
{
    const int tid = threadIdx.x;
    const int lane = tid & 63;
    const int w = tid >> 6;
    const int quad = lane >> 4;
    const int l16 = lane & 15;
    const int n_base = w * 64;
    const int blk = blockIdx.x;  // 64 vocab rows per block

    floatx4 acc[4][4] = {};
    for (int k0 = 0; k0 < DIM; k0 += 32) {
        short8 af[4], bf[4];
#pragma unroll
        for (int mi = 0; mi < 4; mi++) {
            int v = blk * 64 + mi * 16 + l16;
            float4 x0 = {0, 0, 0, 0}, x1 = {0, 0, 0, 0};
            if (v < VOCAB) {
                x0 = *(const float4*)(emb + (size_t)v * DIM + k0 + quad * 8);
                x1 = *(const float4*)(emb + (size_t)v * DIM + k0 + quad * 8 + 4);
            }
            union { short8 s; unsigned short h[8]; } u;
            u.h[0] = f2bf(x0.x); u.h[1] = f2bf(x0.y); u.h[2] = f2bf(x0.z); u.h[3] = f2bf(x0.w);
            u.h[4] = f2bf(x1.x); u.h[5] = f2bf(x1.y); u.h[6] = f2bf(x1.z); u.h[7] = f2bf(x1.w);
            af[mi] = u.s;
        }
#pragma unroll
        for (int ni = 0; ni < 4; ni++) {
            int n = n_base + ni * 16 + l16;
            union { short8 s; unsigned short h[8]; } u;
#pragma unroll
            for (int j = 0; j < 8; j++)
                u.h[j] = f2bf(Q[(size_t)(k0 + quad * 8 + j) * DIM + n]);
            bf[ni] = u.s;
        }
#pragma unroll
        for (int mi = 0; mi < 4; mi++)
#pragma unroll
            for (int ni = 0; ni < 4; ni++)
                acc[mi][ni] = __builtin_amdgcn_mfma_f32_16x16x32_bf16(af[mi], bf[ni], acc[mi][ni], 0, 0, 0);
    }
#pragma unroll
    for (int mi = 0; mi < 4; mi++)
#pragma unroll
        for (int ni = 0; ni < 4; ni++) {
            int col = n_base + ni * 16 + l16;
#pragma unroll
            for (int r = 0; r < 4; r++) {
                int v = blk * 64 + mi * 16 + quad * 4 + r;
                if (v < VOCAB) P[(size_t)v * DIM + col] = __float2bfloat16(acc[mi][ni][r]);
            }
        }
}

// ---- main fused kernel: one block per batch, 8 waves ----
// __launch_bounds__(512, 4): 4 waves/EU * 4 EU = 1024 thr = 2 blocks/CU.
// Forces VGPR <= 128. Phase C is split into two mi-passes (acc[2][4] = 32 VGPR
// instead of acc[4][4] = 64) with the epilogue fused into each pass, so peak
// live registers stay well under the 128 cap. The B-fragment gather is repeated
// per pass (K=64 only: +64 ds_read_u16/wave — noise vs. doubled occupancy).
__global__ __launch_bounds__(512, 4) void fused_attn_kernel(
    const int* __restrict__ ids_en,
    const int* __restrict__ ids_fr,
    const float* __restrict__ emb,            // fp32 [300][512] (epilogue residual)
    const __hip_bfloat16* __restrict__ P,     // bf16 [300][512] = emb @ W
    float* __restrict__ out)                  // fp32 [B][64][512]
{
    __shared__ __align__(16) unsigned short qk[SEQ * LDQ];   // qkv rows (66048 B)
    __shared__ __align__(16) unsigned short sc[SEQ * LDSC];  // scores bf16 (9216 B)
    __shared__ float maskS[SEQ];
    __shared__ int idsF[SEQ];
    __shared__ int idsE[SEQ];

    const int b = blockIdx.x;
    const int tid = threadIdx.x;
    const int lane = tid & 63;
    const int w = tid >> 6;
    const int quad = lane >> 4;
    const int l16 = lane & 15;
    const int n_base = w * 64;

    if (tid < SEQ) {
        int idf = ids_fr[b * SEQ + tid];
        idsF[tid] = idf;
        maskS[tid] = (idf != 0) ? 1.0f : 0.0f;
        idsE[tid] = ids_en[b * SEQ + tid];
    }
    __syncthreads();

    // ---- stage qkv = P[ids_fr] into LDS (16B global reads, 2x8B LDS writes) ----
    for (int c = tid; c < SEQ * (DIM / 8); c += 512) {
        int row = c >> 6;
        int ch  = c & 63;
        uint4 v = *(const uint4*)(P + (size_t)idsF[row] * DIM + ch * 8);
        unsigned short* dst = qk + row * LDQ + ch * 8;
        *(uint2*)dst = make_uint2(v.x, v.y);
        *(uint2*)(dst + 4) = make_uint2(v.z, v.w);
    }
    __syncthreads();

    // ---- Phase B: scores = (qkv @ qkv^T) * mask[k]  (16 16x16 tiles, 2/wave, K=512) ----
    {
        floatx4 accS[2] = {};
        const int t0 = w * 2;
        const int qi = t0 >> 2;  // same for both tiles of this wave
        for (int k0 = 0; k0 < DIM; k0 += 32) {
            short8 aa = ld8(qk + (qi * 16 + l16) * LDQ + k0 + quad * 8);
#pragma unroll
            for (int i = 0; i < 2; i++) {
                int ki = (t0 + i) & 3;
                short8 bb = ld8(qk + (ki * 16 + l16) * LDQ + k0 + quad * 8);
                accS[i] = __builtin_amdgcn_mfma_f32_16x16x32_bf16(aa, bb, accS[i], 0, 0, 0);
            }
        }
#pragma unroll
        for (int i = 0; i < 2; i++) {
            int ki = (t0 + i) & 3;
            float m = maskS[ki * 16 + l16];
#pragma unroll
            for (int r = 0; r < 4; r++) {
                int row = qi * 16 + quad * 4 + r;
                sc[row * LDSC + ki * 16 + l16] = f2bf(accS[i][r] * m);
            }
        }
    }
    __syncthreads();

    // ---- Phase C + epilogue, two passes of 2 row-tiles each ----
    // Pass p computes encoded rows [p*32, p*32+32) for this wave's 64-col slice
    // and immediately streams out = emb[ids_en] + encoded. acc live = 32 VGPR.
    const size_t out_base = (size_t)b * SEQ * DIM;
#pragma unroll
    for (int p = 0; p < 2; p++) {
        floatx4 acc[2][4] = {};
        for (int k0 = 0; k0 < SEQ; k0 += 32) {
            short8 af[2];
#pragma unroll
            for (int mi = 0; mi < 2; mi++)
                af[mi] = *(const short8*)(sc + ((p * 2 + mi) * 16 + l16) * LDSC + k0 + quad * 8);
#pragma unroll
            for (int ni = 0; ni < 4; ni++) {
                short8 bb;
#pragma unroll
                for (int j = 0; j < 8; j++)
                    ((unsigned short*)&bb)[j] = qk[(k0 + quad * 8 + j) * LDQ + n_base + ni * 16 + l16];
#pragma unroll
                for (int mi = 0; mi < 2; mi++)
                    acc[mi][ni] = __builtin_amdgcn_mfma_f32_16x16x32_bf16(af[mi], bb, acc[mi][ni], 0, 0, 0);
            }
        }
#pragma unroll
        for (int mi = 0; mi < 2; mi++)
#pragma unroll
            for (int ni = 0; ni < 4; ni++) {
                int col = n_base + ni * 16 + l16;
#pragma unroll
                for (int r = 0; r < 4; r++) {
                    int row = (p * 2 + mi) * 16 + quad * 4 + r;
                    out[out_base + (size_t)row * DIM + col] =
                        emb[(size_t)idsE[row] * DIM + col] + acc[mi][ni][r];
                }
            }
    }
}

extern "C" void kernel_launch(void* const* d_in, const int* in_sizes, int n_in,
                              void* d_out, int out_size, void* d_ws, size_t ws_size,
                              hipStream_t stream) {
    const int* ids_en = (const int*)d_in[0];
    const int* ids_fr = (const int*)d_in[1];
    const float* emb  = (const float*)d_in[2];
    const float* Qd   = (const float*)d_in[3];
    float* out = (float*)d_out;

    const int B = in_sizes[0] / SEQ;  // 1024

    __hip_bfloat16* P = (__hip_bfloat16*)d_ws;  // 300*512*2 = 307200 B

    proj_kernel<<<(VOCAB + 63) / 64, 512, 0, stream>>>(emb, Qd, P);
    fused_attn_kernel<<<B, 512, 0, stream>>>(ids_en, ids_fr, emb, P, out);
}

// Round 2
// 164.821 us; speedup vs baseline: 1.2029x; 1.1897x over previous
//
#include <hip/hip_runtime.h>
#include <hip/hip_bf16.h>

#define SEQ 64
#define DIM 512
#define VOCAB 300
#define LDQ 516   // ushort row stride for qkv LDS: 1032B rows (8B-aligned). 8-row quad stride
                  // = 2064 dwords = 16 mod 32 banks -> 2-way aliasing only (free). A 16B-aligned
                  // stride (520) makes quad strides = 0 mod 32 -> 8-way conflicts in Phase C.
#define LDSC 72   // ushort row stride for scores (144B rows, 16B-aligned)

typedef __attribute__((ext_vector_type(8))) short short8;   // 8 bf16 (MFMA A/B frag)
typedef __attribute__((ext_vector_type(4))) float floatx4;  // MFMA C/D frag

static __device__ inline unsigned short f2bf(float x) {
    __hip_bfloat16 t = __float2bfloat16(x);
    return *reinterpret_cast<unsigned short*>(&t);
}

// load 8 bf16 from an 8B-aligned LDS address (two uint2 -> ds_read2_b64)
static __device__ inline short8 ld8(const unsigned short* p) {
    union { short8 s; uint2 u[2]; } r;
    r.u[0] = *(const uint2*)p;
    r.u[1] = *(const uint2*)(p + 4);
    return r.s;
}

// ---- prep: P = emb @ Qdense (300x512 @ 512x512, bf16 out).
// One 16x16 output tile per WAVE: grid (32 n-tiles) x (19 m-tiles), 64 thr.
// 608 single-wave blocks vs the old 5x512 launch — the old version left 251
// CUs idle and serialized ~1.3 MB of L2-latency scalar loads behind 8 waves.
// Latency-bound, so parallelism (not coalescing) is the lever here.
__global__ __launch_bounds__(64) void proj_kernel(
    const float* __restrict__ emb,   // fp32 [300][512]
    const float* __restrict__ Q,     // fp32 [512][512], row-major [k][n]
    __hip_bfloat16* __restrict__ P)  // bf16 [300][512]
{
    const int lane = threadIdx.x & 63;
    const int quad = lane >> 4;
    const int l16 = lane & 15;
    const int nt = blockIdx.x;       // 0..31  (column tile)
    const int mt = blockIdx.y;       // 0..18  (row tile; last is partial)
    const int n = nt * 16 + l16;
    const int vrow = mt * 16 + l16;  // A-operand row this lane loads

    floatx4 acc = {};
#pragma unroll 4
    for (int k0 = 0; k0 < DIM; k0 += 32) {
        float4 x0 = {0, 0, 0, 0}, x1 = {0, 0, 0, 0};
        if (vrow < VOCAB) {
            x0 = *(const float4*)(emb + (size_t)vrow * DIM + k0 + quad * 8);
            x1 = *(const float4*)(emb + (size_t)vrow * DIM + k0 + quad * 8 + 4);
        }
        union { short8 s; unsigned short h[8]; } ua;
        ua.h[0] = f2bf(x0.x); ua.h[1] = f2bf(x0.y); ua.h[2] = f2bf(x0.z); ua.h[3] = f2bf(x0.w);
        ua.h[4] = f2bf(x1.x); ua.h[5] = f2bf(x1.y); ua.h[6] = f2bf(x1.z); ua.h[7] = f2bf(x1.w);

        union { short8 s; unsigned short h[8]; } ub;
#pragma unroll
        for (int j = 0; j < 8; j++)
            ub.h[j] = f2bf(Q[(size_t)(k0 + quad * 8 + j) * DIM + n]);

        acc = __builtin_amdgcn_mfma_f32_16x16x32_bf16(ua.s, ub.s, acc, 0, 0, 0);
    }
#pragma unroll
    for (int r = 0; r < 4; r++) {
        int v = mt * 16 + quad * 4 + r;
        if (v < VOCAB) P[(size_t)v * DIM + n] = __float2bfloat16(acc[r]);
    }
}

// ---- main fused kernel: one block per batch, 8 waves ----
// __launch_bounds__(512, 4): 4 waves/EU * 4 EU = 1024 thr = 2 blocks/CU.
// Phase C split into two mi-passes (acc[2][4] = 32 VGPR) with fused epilogue.
__global__ __launch_bounds__(512, 4) void fused_attn_kernel(
    const int* __restrict__ ids_en,
    const int* __restrict__ ids_fr,
    const float* __restrict__ emb,            // fp32 [300][512] (epilogue residual)
    const __hip_bfloat16* __restrict__ P,     // bf16 [300][512] = emb @ W
    float* __restrict__ out)                  // fp32 [B][64][512]
{
    __shared__ __align__(16) unsigned short qk[SEQ * LDQ];   // qkv rows (66048 B)
    __shared__ __align__(16) unsigned short sc[SEQ * LDSC];  // scores bf16 (9216 B)
    __shared__ float maskS[SEQ];
    __shared__ int idsF[SEQ];
    __shared__ int idsE[SEQ];

    const int b = blockIdx.x;
    const int tid = threadIdx.x;
    const int lane = tid & 63;
    const int w = tid >> 6;
    const int quad = lane >> 4;
    const int l16 = lane & 15;
    const int n_base = w * 64;

    if (tid < SEQ) {
        int idf = ids_fr[b * SEQ + tid];
        idsF[tid] = idf;
        maskS[tid] = (idf != 0) ? 1.0f : 0.0f;
        idsE[tid] = ids_en[b * SEQ + tid];
    }
    __syncthreads();

    // ---- stage qkv = P[ids_fr] into LDS (16B global reads, 2x8B LDS writes) ----
    for (int c = tid; c < SEQ * (DIM / 8); c += 512) {
        int row = c >> 6;
        int ch  = c & 63;
        uint4 v = *(const uint4*)(P + (size_t)idsF[row] * DIM + ch * 8);
        unsigned short* dst = qk + row * LDQ + ch * 8;
        *(uint2*)dst = make_uint2(v.x, v.y);
        *(uint2*)(dst + 4) = make_uint2(v.z, v.w);
    }
    __syncthreads();

    // ---- Phase B: scores = (qkv @ qkv^T) * mask[k]  (16 16x16 tiles, 2/wave, K=512) ----
    {
        floatx4 accS[2] = {};
        const int t0 = w * 2;
        const int qi = t0 >> 2;  // same for both tiles of this wave
        for (int k0 = 0; k0 < DIM; k0 += 32) {
            short8 aa = ld8(qk + (qi * 16 + l16) * LDQ + k0 + quad * 8);
#pragma unroll
            for (int i = 0; i < 2; i++) {
                int ki = (t0 + i) & 3;
                short8 bb = ld8(qk + (ki * 16 + l16) * LDQ + k0 + quad * 8);
                accS[i] = __builtin_amdgcn_mfma_f32_16x16x32_bf16(aa, bb, accS[i], 0, 0, 0);
            }
        }
#pragma unroll
        for (int i = 0; i < 2; i++) {
            int ki = (t0 + i) & 3;
            float m = maskS[ki * 16 + l16];
#pragma unroll
            for (int r = 0; r < 4; r++) {
                int row = qi * 16 + quad * 4 + r;
                sc[row * LDSC + ki * 16 + l16] = f2bf(accS[i][r] * m);
            }
        }
    }
    __syncthreads();

    // ---- Phase C + epilogue, two passes of 2 row-tiles each ----
    const size_t out_base = (size_t)b * SEQ * DIM;
#pragma unroll
    for (int p = 0; p < 2; p++) {
        floatx4 acc[2][4] = {};
        for (int k0 = 0; k0 < SEQ; k0 += 32) {
            short8 af[2];
#pragma unroll
            for (int mi = 0; mi < 2; mi++)
                af[mi] = *(const short8*)(sc + ((p * 2 + mi) * 16 + l16) * LDSC + k0 + quad * 8);
#pragma unroll
            for (int ni = 0; ni < 4; ni++) {
                short8 bb;
#pragma unroll
                for (int j = 0; j < 8; j++)
                    ((unsigned short*)&bb)[j] = qk[(k0 + quad * 8 + j) * LDQ + n_base + ni * 16 + l16];
#pragma unroll
                for (int mi = 0; mi < 2; mi++)
                    acc[mi][ni] = __builtin_amdgcn_mfma_f32_16x16x32_bf16(af[mi], bb, acc[mi][ni], 0, 0, 0);
            }
        }
#pragma unroll
        for (int mi = 0; mi < 2; mi++)
#pragma unroll
            for (int ni = 0; ni < 4; ni++) {
                int col = n_base + ni * 16 + l16;
#pragma unroll
                for (int r = 0; r < 4; r++) {
                    int row = (p * 2 + mi) * 16 + quad * 4 + r;
                    out[out_base + (size_t)row * DIM + col] =
                        emb[(size_t)idsE[row] * DIM + col] + acc[mi][ni][r];
                }
            }
    }
}

extern "C" void kernel_launch(void* const* d_in, const int* in_sizes, int n_in,
                              void* d_out, int out_size, void* d_ws, size_t ws_size,
                              hipStream_t stream) {
    const int* ids_en = (const int*)d_in[0];
    const int* ids_fr = (const int*)d_in[1];
    const float* emb  = (const float*)d_in[2];
    const float* Qd   = (const float*)d_in[3];
    float* out = (float*)d_out;

    const int B = in_sizes[0] / SEQ;  // 1024

    __hip_bfloat16* P = (__hip_bfloat16*)d_ws;  // 300*512*2 = 307200 B

    proj_kernel<<<dim3(32, 19), 64, 0, stream>>>(emb, Qd, P);
    fused_attn_kernel<<<B, 512, 0, stream>>>(ids_en, ids_fr, emb, P, out);
}